// Round 14
// baseline (125.691 us; speedup 1.0000x reference)
//
#include <hip/hip_runtime.h>
#include <stdint.h>
#include <stddef.h>

// b=4, n=1024, dim=512, heads=8, dh=64.
// Layouts (fragment-native, r6):
//   qb  [4096][512]  bf16  Q, pre-scaled 1/16
//   kh  [b*8+h][j/16][8 dhb][16 j][8 dh] bf16  (128 KB/head)
//   vt3 [b*8+h][j/8][64 d][8 j] bf16           (128 KB/head)
// R14: xb eliminated — QKV gemm reads x (fp32) directly, converting during
// A-staging (reg-stage + v_cvt_pk_bf16_f32 + ds_write_b128). Same RNE path
// as the old convert_all -> absmax must be bit-identical.

typedef __attribute__((ext_vector_type(4))) float f32x4;
typedef __attribute__((ext_vector_type(2))) float f32x2;
typedef __attribute__((ext_vector_type(8))) short bf16x8;
typedef __attribute__((ext_vector_type(4))) uint32_t u32x4;
typedef __attribute__((ext_vector_type(2))) uint32_t u32x2;

__device__ inline unsigned short f2bf(float f) {
    union { float f; uint32_t u; } cv; cv.f = f;
    uint32_t u = cv.u;
    return (unsigned short)((u + 0x7fffu + ((u >> 16) & 1u)) >> 16);
}
// HW packed convert: 2 fp32 -> 2 bf16 (RNE), single VOP3.
__device__ inline uint32_t packbf2(float lo, float hi) {
    uint32_t r;
    asm("v_cvt_pk_bf16_f32 %0, %1, %2" : "=v"(r) : "v"(lo), "v"(hi));
    return r;
}
__device__ inline void gl_lds16(const short* g, short* l) {
    __builtin_amdgcn_global_load_lds(
        (const __attribute__((address_space(1))) void*)g,
        (__attribute__((address_space(3))) void*)l, 16, 0, 0);
}
// packed-fp32 helpers -> v_pk_max_f32 / v_pk_fma_f32
__device__ inline f32x2 vmax2(f32x2 a, f32x2 b) { return __builtin_elementwise_max(a, b); }
__device__ inline f32x2 vfma2(f32x2 a, f32x2 b, f32x2 c) { return __builtin_elementwise_fma(a, b, c); }

// 16-lane (DPP row) rotate-reduce (r7): row_ror 8/4/2/1 within 16-lane rows.
template<int C> __device__ inline float rsum(float x) {
    int v = __builtin_amdgcn_update_dpp(0, __builtin_bit_cast(int, x), C, 0xf, 0xf, true);
    return x + __builtin_bit_cast(float, v);
}
template<int C> __device__ inline float rmax(float x) {
    int v = __builtin_amdgcn_update_dpp(0, __builtin_bit_cast(int, x), C, 0xf, 0xf, true);
    return fmaxf(x, __builtin_bit_cast(float, v));
}
__device__ inline float red16_sum(float x) {
    x = rsum<0x128>(x); x = rsum<0x124>(x); x = rsum<0x122>(x); x = rsum<0x121>(x);
    return x;
}
__device__ inline float red16_max(float x) {
    x = rmax<0x128>(x); x = rmax<0x124>(x); x = rmax<0x122>(x); x = rmax<0x121>(x);
    return x;
}

// ---------------------------------------------------------------------------
// convert (weights only now): w_qkv [512][1536] -> wqkvt [1536][512] bf16 (T);
//                             w_out [512][512] -> woutt [512][512] bf16 (T)
// ---------------------------------------------------------------------------
__global__ __launch_bounds__(256) void convert_all(const float* __restrict__ wqkv,
                                                   const float* __restrict__ wout,
                                                   short* __restrict__ wqkvt,
                                                   short* __restrict__ woutt) {
    __shared__ float tl[32][33];
    const int bid = blockIdx.x;
    const int t = threadIdx.x;
    const float* src; short* dst; int NC, tn, tk;
    if (bid < 768) {
        tn = bid % 48; tk = bid / 48; src = wqkv; dst = wqkvt; NC = 1536;
    } else {
        int idx = bid - 768; tn = idx % 16; tk = idx / 16; src = wout; dst = woutt; NC = 512;
    }
    const int row = t >> 3, c4 = (t & 7) * 4;
    f32x4 v = *(const f32x4*)(src + (size_t)(tk * 32 + row) * NC + tn * 32 + c4);
    tl[row][c4 + 0] = v[0]; tl[row][c4 + 1] = v[1];
    tl[row][c4 + 2] = v[2]; tl[row][c4 + 3] = v[3];
    __syncthreads();
    float a = tl[c4 + 0][row], b = tl[c4 + 1][row];
    float c = tl[c4 + 2][row], d = tl[c4 + 3][row];
    u32x2 o = {packbf2(a, b), packbf2(c, d)};
    *(u32x2*)(dst + (size_t)(tn * 32 + row) * 512 + tk * 32 + c4) = o;
}

// ---------------------------------------------------------------------------
// bf16 MFMA GEMM: BMm x BNn tile, 256 thr (4 waves, 2x2), BK=32, 2-phase dbuf.
// MODE 0 (BM=128, BN=128): A = x fp32, converted in A-staging (reg-stage +
//   cvt_pk + ds_write_b128; loads issued before compute, write after).
//   bn<4 -> qb (q*1/16); bn 4..7 -> kh; bn>=8 -> vt3.
// MODE 1 (BM=64, BN=64): A bf16 via gl_lds16; fp32 out [M][512].
// ---------------------------------------------------------------------------
template<int NB, int MODE, int BM, int BN>
__global__ __launch_bounds__(256) void gemm_bf16(const void* __restrict__ Ap,
                                                 const short* __restrict__ Bt,
                                                 void* __restrict__ outp,
                                                 short* __restrict__ vt3,
                                                 short* __restrict__ kh) {
    constexpr int MFR = BM / 32;            // m-fragments per wave
    constexpr int NFR = BN / 32;            // n-fragments per wave
    constexpr int AI = BM / 64;             // stage sub-iters for A
    constexpr int BI = BN / 64;
    __shared__ __align__(16) short As[2][BM * 32];
    __shared__ __align__(16) short Bs[2][BN * 32];
    const int t = threadIdx.x;
    const int lane = t & 63;
    const int wv = t >> 6;
    const int quad = lane >> 4;
    const int l16 = lane & 15;
    const int bm = blockIdx.x / NB;
    const int bn = blockIdx.x % NB;
    const int wm = (wv & 1) * (BM / 2), wn = (wv >> 1) * (BN / 2);

    f32x4 acc[MFR][NFR];
    #pragma unroll
    for (int i = 0; i < MFR; i++)
        #pragma unroll
        for (int j = 0; j < NFR; j++) acc[i][j] = (f32x4){0.f, 0.f, 0.f, 0.f};

    const int sr = t >> 2, sc = (t & 3) * 8;
    const float* Xbase = (const float*)Ap + (size_t)(bm * BM + sr) * 512 + sc;  // MODE 0
    const short* Abase = (const short*)Ap + (size_t)(bm * BM + sr) * 512 + sc;  // MODE 1
    const short* Bbase = Bt + (size_t)(bn * BN + sr) * 512 + sc;

    f32x4 ar[AI][2];
    // prologue: stage kt=0 into buf 0
    if (MODE == 0) {
        #pragma unroll
        for (int i = 0; i < AI; i++) {
            const float* xp = Xbase + (size_t)(64 * i) * 512;
            ar[i][0] = *(const f32x4*)xp;
            ar[i][1] = *(const f32x4*)(xp + 4);
        }
        #pragma unroll
        for (int i = 0; i < AI; i++) {
            u32x4 pk = {packbf2(ar[i][0][0], ar[i][0][1]), packbf2(ar[i][0][2], ar[i][0][3]),
                        packbf2(ar[i][1][0], ar[i][1][1]), packbf2(ar[i][1][2], ar[i][1][3])};
            *(u32x4*)(&As[0][(64 * i + sr) * 32 + sc]) = pk;
        }
    } else {
        #pragma unroll
        for (int i = 0; i < AI; i++)
            gl_lds16(Abase + (size_t)(64 * i) * 512, &As[0][64 * i * 32 + t * 8]);
    }
    #pragma unroll
    for (int i = 0; i < BI; i++)
        gl_lds16(Bbase + (size_t)(64 * i) * 512, &Bs[0][64 * i * 32 + t * 8]);
    __syncthreads();

    for (int kt = 0; kt < 16; kt++) {
        const int cur = kt & 1;
        if (kt < 15) {                       // issue next-tile loads FIRST
            if (MODE == 0) {
                #pragma unroll
                for (int i = 0; i < AI; i++) {
                    const float* xp = Xbase + (size_t)(64 * i) * 512 + (kt + 1) * 32;
                    ar[i][0] = *(const f32x4*)xp;
                    ar[i][1] = *(const f32x4*)(xp + 4);
                }
            } else {
                #pragma unroll
                for (int i = 0; i < AI; i++)
                    gl_lds16(Abase + (size_t)(64 * i) * 512 + (kt + 1) * 32,
                             &As[cur ^ 1][64 * i * 32 + t * 8]);
            }
            #pragma unroll
            for (int i = 0; i < BI; i++)
                gl_lds16(Bbase + (size_t)(64 * i) * 512 + (kt + 1) * 32,
                         &Bs[cur ^ 1][64 * i * 32 + t * 8]);
        }
        bf16x8 af[MFR], bfr[NFR];
        #pragma unroll
        for (int mi = 0; mi < MFR; mi++)
            af[mi] = *(const bf16x8*)(&As[cur][(wm + mi * 16 + l16) * 32 + quad * 8]);
        #pragma unroll
        for (int ni = 0; ni < NFR; ni++)
            bfr[ni] = *(const bf16x8*)(&Bs[cur][(wn + ni * 16 + l16) * 32 + quad * 8]);
        #pragma unroll
        for (int mi = 0; mi < MFR; mi++)
            #pragma unroll
            for (int ni = 0; ni < NFR; ni++)
                acc[mi][ni] = __builtin_amdgcn_mfma_f32_16x16x32_bf16(af[mi], bfr[ni], acc[mi][ni], 0, 0, 0);
        if (MODE == 0 && kt < 15) {          // convert + write A(kt+1) after compute
            #pragma unroll
            for (int i = 0; i < AI; i++) {
                u32x4 pk = {packbf2(ar[i][0][0], ar[i][0][1]), packbf2(ar[i][0][2], ar[i][0][3]),
                            packbf2(ar[i][1][0], ar[i][1][1]), packbf2(ar[i][1][2], ar[i][1][3])};
                *(u32x4*)(&As[cur ^ 1][(64 * i + sr) * 32 + sc]) = pk;
            }
        }
        __syncthreads();                     // drains stage(kt+1) + guards LDS reuse
    }

    if (MODE == 0) {
        if (bn < 4) {
            // Q -> qb [4096][512], scaled 1/16
            short* ob = (short*)outp;
            #pragma unroll
            for (int mi = 0; mi < MFR; mi++)
                #pragma unroll
                for (int ni = 0; ni < NFR; ni++)
                    #pragma unroll
                    for (int rg = 0; rg < 4; rg++)
                        ob[(size_t)(bm * BM + wm + mi * 16 + quad * 4 + rg) * 512
                           + bn * BN + wn + ni * 16 + l16] = (short)f2bf(acc[mi][ni][rg] * 0.0625f);
        } else if (bn < 8) {
            // K -> kh frag layout: head (bb,hh): [j>>4][dh>>3][j&15][dh&7]
            #pragma unroll
            for (int mi = 0; mi < MFR; mi++) {
                int rowb = bm * BM + wm + mi * 16 + quad * 4;
                int bbb = rowb >> 10, jj0 = rowb & 1023;
                #pragma unroll
                for (int ni = 0; ni < NFR; ni++) {
                    int c = bn * BN + wn + ni * 16 + l16 - 512;  // 0..511
                    int hh = c >> 6, dh = c & 63;
                    short* base = kh + (size_t)(bbb * 8 + hh) * 65536
                                  + (size_t)(jj0 >> 4) * 1024 + (dh >> 3) * 128 + (dh & 7);
                    #pragma unroll
                    for (int rg = 0; rg < 4; rg++)
                        base[((jj0 & 15) + rg) * 8] = (short)f2bf(acc[mi][ni][rg]);
                }
            }
        } else {
            // V -> vt3 frag layout: head: [j>>3][d][j&7]
            #pragma unroll
            for (int mi = 0; mi < MFR; mi++) {
                int rowb = bm * BM + wm + mi * 16 + quad * 4;
                int bbb = rowb >> 10, j = rowb & 1023;
                #pragma unroll
                for (int ni = 0; ni < NFR; ni++) {
                    int vcol = bn * BN + wn + ni * 16 + l16 - 1024;  // 0..511
                    int hh = vcol >> 6, dd = vcol & 63;
                    u32x2 pk = {packbf2(acc[mi][ni][0], acc[mi][ni][1]),
                                packbf2(acc[mi][ni][2], acc[mi][ni][3])};
                    *(u32x2*)(vt3 + (size_t)(bbb * 8 + hh) * 65536
                              + (size_t)(j >> 3) * 512 + dd * 8 + (j & 7)) = pk;
                }
            }
        }
    } else {
        float* of = (float*)outp;
        #pragma unroll
        for (int mi = 0; mi < MFR; mi++)
            #pragma unroll
            for (int ni = 0; ni < NFR; ni++)
                #pragma unroll
                for (int rg = 0; rg < 4; rg++)
                    of[(size_t)(bm * BM + wm + mi * 16 + quad * 4 + rg) * 512
                       + bn * BN + wn + ni * 16 + l16] = acc[mi][ni][rg];
    }
}

// ---------------------------------------------------------------------------
// Fused entmax-1.5 attention: 16 query rows/block, 256 thr. (r13 structure)
// ---------------------------------------------------------------------------
__global__ __launch_bounds__(256, 4) void attn_entmax(const short* __restrict__ qb,
                                                      const short* __restrict__ kh,
                                                      const short* __restrict__ vt3,
                                                      short* __restrict__ oheads) {
    __shared__ __align__(16) unsigned char smem[34304];
    short* P_lds = (short*)smem;            // [16][1024] bf16, XOR-swizzled 8-blocks (32768 B)
    float* tbuf = (float*)smem;             // [2][16][268] fp32 transpose buf (34304 B)
    float* osum = (float*)smem;             // [16][68] fp32 (4352 B)
    const int TB = 16 * 268;                // floats per tbuf chunk

    const int t = threadIdx.x;
    const int lane = t & 63;
    const int wv = t >> 6;
    const int quad = lane >> 4;
    const int l16 = lane & 15;

    const int xcd = blockIdx.x & 7;
    const int g = blockIdx.x >> 3;
    const int hb = xcd * 4 + (g >> 6);      // 0..31
    const int rt = g & 63;
    const int bb = hb >> 3, hh = hb & 7;
    const int r0 = rt * 16;

    // Q A-frags from qb [4096][512]; q pre-scaled by 1/16 so z = sim/2
    bf16x8 a0, a1;
    {
        const short* qp = qb + (size_t)(bb * 1024 + r0 + l16) * 512 + hh * 64 + quad * 8;
        a0 = *(const bf16x8*)qp;
        a1 = *(const bf16x8*)(qp + 32);
    }

    const short* khh = kh + (size_t)(bb * 8 + hh) * 65536;
    const short* vb0 = vt3 + (size_t)(bb * 8 + hh) * 65536;

    // ---- scores in 4 column-chunks of 256, transposed to row-owner layout ----
    // zT2[ci*8 + i*2 + (c>>1)][c&1] = z[row quad*4+wv][col ci*256 + i*64 + l16*4 + c]
    f32x2 zT2[32];
    const int rown = quad * 4 + wv;         // owned row

    bf16x8 kc0[4], kc1[4], kn0[4], kn1[4];
    #pragma unroll
    for (int f = 0; f < 4; f++) {           // preload chunk 0 K-frags
        int supl = f >> 1, jj = f & 1;
        int jtile = supl * 8 + (wv + 4 * jj);
        const short* kp = khh + (size_t)jtile * 1024 + l16 * 8;
        kc0[f] = *(const bf16x8*)(kp + quad * 128);
        kc1[f] = *(const bf16x8*)(kp + (4 + quad) * 128);
    }

    #pragma unroll
    for (int ci = 0; ci < 4; ci++) {
        const int cb = (ci & 1) * TB;
        if (ci < 3) {                       // issue next chunk's K loads FIRST
            #pragma unroll
            for (int f = 0; f < 4; f++) {
                int supl = f >> 1, jj = f & 1;
                int jtile = ((ci + 1) * 2 + supl) * 8 + (wv + 4 * jj);
                const short* kp = khh + (size_t)jtile * 1024 + l16 * 8;
                kn0[f] = *(const bf16x8*)(kp + quad * 128);
                kn1[f] = *(const bf16x8*)(kp + (4 + quad) * 128);
            }
        }
        #pragma unroll
        for (int f = 0; f < 4; f++) {
            int supl = f >> 1, jj = f & 1;
            f32x4 acc = {0.f, 0.f, 0.f, 0.f};
            acc = __builtin_amdgcn_mfma_f32_16x16x32_bf16(a0, kc0[f], acc, 0, 0, 0);
            acc = __builtin_amdgcn_mfma_f32_16x16x32_bf16(a1, kc1[f], acc, 0, 0, 0);
            int colc = supl * 128 + (wv + 4 * jj) * 16 + l16;
            #pragma unroll
            for (int rg = 0; rg < 4; rg++)
                tbuf[cb + (quad * 4 + rg) * 268 + colc] = acc[rg];
        }
        __syncthreads();                    // tbuf[cb] complete (also orders reuse)
        #pragma unroll
        for (int i = 0; i < 4; i++) {
            f32x4 v = *(const f32x4*)(tbuf + cb + rown * 268 + i * 64 + l16 * 4);
            zT2[ci * 8 + i * 2 + 0] = (f32x2){v[0], v[1]};
            zT2[ci * 8 + i * 2 + 1] = (f32x2){v[2], v[3]};
        }
        #pragma unroll
        for (int f = 0; f < 4; f++) { kc0[f] = kn0[f]; kc1[f] = kn1[f]; }
    }
    __syncthreads();                        // last readback done; smem reusable

    // ---- init: mx + full-support closed-form tau, clamped to bracket ----
    float tau;
    {
        f32x2 m2 = zT2[0], p2 = zT2[0];
        f32x2 q2 = zT2[0] * zT2[0];
        #pragma unroll
        for (int i = 1; i < 32; i++) {
            f32x2 v = zT2[i];
            m2 = vmax2(m2, v);
            p2 = p2 + v;
            q2 = vfma2(v, v, q2);
        }
        float mx = red16_max(fmaxf(m2[0], m2[1]));
        float s1 = red16_sum(p2[0] + p2[1]);
        float s2 = red16_sum(q2[0] + q2[1]);
        float mean = s1 * (1.0f / 1024.0f);
        float disc = fmaxf(mean * mean - (s2 - 1.0f) * (1.0f / 1024.0f), 0.0f);
        tau = mean - __builtin_sqrtf(disc);
        tau = fminf(tau, mx - 0.03125f);    // tau* <= mx - 1/sqrt(n)
        tau = fmaxf(tau, mx - 1.0f);        // tau* >= mx - 1
    }

    // ---- Newton (barrier-free, packed fp32): f(tau)=sum relu(z-tau)^2 - 1 ----
    const f32x2 zero2 = {0.f, 0.f};
    #pragma unroll 1
    for (int it = 0; it < 5; it++) {
        f32x2 tau2 = {tau, tau};
        f32x2 s1a = zero2, s1b = zero2, s2a = zero2, s2b = zero2;
        #pragma unroll
        for (int i = 0; i < 16; i++) {
            f32x2 ra = vmax2(zT2[i * 2] - tau2, zero2);
            f32x2 rb = vmax2(zT2[i * 2 + 1] - tau2, zero2);
            s1a = s1a + ra; s1b = s1b + rb;
            s2a = vfma2(ra, ra, s2a); s2b = vfma2(rb, rb, s2b);
        }
        float s1 = red16_sum((s1a[0] + s1a[1]) + (s1b[0] + s1b[1]));
        float s2 = red16_sum((s2a[0] + s2a[1]) + (s2b[0] + s2b[1]));
        tau += (s2 - 1.0f) * 0.5f * __builtin_amdgcn_rcpf(s1);
    }

    // ---- P = relu(z-tau)^2 -> swizzled P_lds (bf16, A-operand layout) ----
    // off(row, j) = row*1024 + ((jb ^ (row&7))<<3) + (j&7), jb = j>>3
    {
        const f32x2 tau2 = {tau, tau};
        const int dg = l16;
        const int ra = rown & 7;
        #pragma unroll
        for (int ci = 0; ci < 4; ci++)
            #pragma unroll
            for (int i = 0; i < 4; i++) {
                f32x2 r01 = vmax2(zT2[ci * 8 + i * 2] - tau2, zero2);
                f32x2 r23 = vmax2(zT2[ci * 8 + i * 2 + 1] - tau2, zero2);
                f32x2 p01 = r01 * r01, p23 = r23 * r23;
                u32x2 pk = {packbf2(p01[0], p01[1]), packbf2(p23[0], p23[1])};
                int jb = ci * 32 + i * 8 + (dg >> 1);
                *(u32x2*)(P_lds + rown * 1024 + ((jb ^ ra) << 3) + (dg & 1) * 4) = pk;
            }
    }
    __syncthreads();

    // ---- PV from vt3 frag layout: O[r][d] += P[r][j] V[j][d] ----
    f32x4 oacc[4];
    #pragma unroll
    for (int nt = 0; nt < 4; nt++) oacc[nt] = (f32x4){0.f, 0.f, 0.f, 0.f};
    const int lra = l16 & 7;
    bf16x8 bv[4], bvn[4];
    {
        int jb0 = wv * 4 + quad;            // sup = 0
        const short* vs = vb0 + (size_t)jb0 * 512;
        #pragma unroll
        for (int nt = 0; nt < 4; nt++)
            bv[nt] = *(const bf16x8*)(vs + (nt * 16 + l16) * 8);
    }
    #pragma unroll
    for (int sup = 0; sup < 8; sup++) {
        int jb = sup * 16 + wv * 4 + quad;
        bf16x8 pf = *(const bf16x8*)(P_lds + l16 * 1024 + ((jb ^ lra) << 3));
        if (sup < 7) {                      // prefetch next sup's V-frags
            const short* vs = vb0 + (size_t)(jb + 16) * 512;
            #pragma unroll
            for (int nt = 0; nt < 4; nt++)
                bvn[nt] = *(const bf16x8*)(vs + (nt * 16 + l16) * 8);
        }
        __builtin_amdgcn_s_setprio(1);
        #pragma unroll
        for (int nt = 0; nt < 4; nt++)
            oacc[nt] = __builtin_amdgcn_mfma_f32_16x16x32_bf16(pf, bv[nt], oacc[nt], 0, 0, 0);
        __builtin_amdgcn_s_setprio(0);
        #pragma unroll
        for (int nt = 0; nt < 4; nt++) bv[nt] = bvn[nt];
    }
    __syncthreads();                        // all P reads done; overlay osum

    #pragma unroll
    for (int nt = 0; nt < 4; nt++)
        #pragma unroll
        for (int rg = 0; rg < 4; rg++)
            osum[(wv * 16 + quad * 4 + rg) * 68 + nt * 16 + l16] = oacc[nt][rg];
    __syncthreads();
    #pragma unroll
    for (int i = 0; i < 2; i++) {
        int idx = t + 256 * i;
        int r = idx >> 5, dp = idx & 31;
        float e0 = 0.f, e1 = 0.f;
        #pragma unroll
        for (int w = 0; w < 4; w++) {
            e0 += osum[(w * 16 + r) * 68 + dp * 2];
            e1 += osum[(w * 16 + r) * 68 + dp * 2 + 1];
        }
        *(uint32_t*)(oheads + (size_t)(bb * 1024 + r0 + r) * 512 + hh * 64 + dp * 2) = packbf2(e0, e1);
    }
}

// ---------------------------------------------------------------------------
extern "C" void kernel_launch(void* const* d_in, const int* in_sizes, int n_in,
                              void* d_out, int out_size, void* d_ws, size_t ws_size,
                              hipStream_t stream) {
    (void)in_sizes; (void)n_in; (void)out_size; (void)ws_size;
    const float* x     = (const float*)d_in[0];
    const float* w_qkv = (const float*)d_in[1];
    const float* w_out = (const float*)d_in[2];
    float* out = (float*)d_out;

    char* ws = (char*)d_ws;
    short* qb    = (short*)(ws);                        // 4,194,304 B  Q [4096][512]
    short* kh    = (short*)(ws + 4194304);              // 4,194,304 B  K frag-layout
    short* vt3   = (short*)(ws + 8388608);              // 4,194,304 B  V frag-layout
    short* ohead = (short*)(ws + 12582912);             // 4,194,304 B
    short* wqkvt = (short*)(ws + 16777216);             // 1,572,864 B
    short* woutt = (short*)(ws + 18350080);             //   524,288 B

    convert_all<<<dim3(1024), dim3(256), 0, stream>>>(w_qkv, w_out, wqkvt, woutt);
    gemm_bf16<12, 0, 128, 128><<<dim3(32 * 12), dim3(256), 0, stream>>>((const void*)x, wqkvt, (void*)qb, vt3, kh);
    attn_entmax<<<dim3(2048), dim3(256), 0, stream>>>(qb, kh, vt3, ohead);
    gemm_bf16<8, 1, 64, 64><<<dim3(64 * 8), dim3(256), 0, stream>>>((const void*)ohead, woutt, (void*)out, nullptr, nullptr);
}

// Round 15
// 121.839 us; speedup vs baseline: 1.0316x; 1.0316x over previous
//
#include <hip/hip_runtime.h>
#include <stdint.h>
#include <stddef.h>

// b=4, n=1024, dim=512, heads=8, dh=64.
// Layouts (fragment-native, r6):
//   qb  [4096][512]  bf16  Q, pre-scaled 1/16
//   kh  [b*8+h][j/16][8 dhb][16 j][8 dh] bf16  (128 KB/head)
//   vt3 [b*8+h][j/8][64 d][8 j] bf16           (128 KB/head)
// R15 = r13 restored (best measured: 123.1 us). R14's in-GEMM convert fusion
// reverted: reg-staged A (load->cvt_pk->ds_write in the barrier window) lost
// ~2.5 us vs async gl_lds16 (T14: reg-staging loses to global_load_lds when
// the kernel isn't BW-bound).

typedef __attribute__((ext_vector_type(4))) float f32x4;
typedef __attribute__((ext_vector_type(2))) float f32x2;
typedef __attribute__((ext_vector_type(8))) short bf16x8;
typedef __attribute__((ext_vector_type(4))) uint32_t u32x4;
typedef __attribute__((ext_vector_type(2))) uint32_t u32x2;

__device__ inline unsigned short f2bf(float f) {
    union { float f; uint32_t u; } cv; cv.f = f;
    uint32_t u = cv.u;
    return (unsigned short)((u + 0x7fffu + ((u >> 16) & 1u)) >> 16);
}
// HW packed convert: 2 fp32 -> 2 bf16 (RNE), single VOP3.
__device__ inline uint32_t packbf2(float lo, float hi) {
    uint32_t r;
    asm("v_cvt_pk_bf16_f32 %0, %1, %2" : "=v"(r) : "v"(lo), "v"(hi));
    return r;
}
__device__ inline void gl_lds16(const short* g, short* l) {
    __builtin_amdgcn_global_load_lds(
        (const __attribute__((address_space(1))) void*)g,
        (__attribute__((address_space(3))) void*)l, 16, 0, 0);
}
// packed-fp32 helpers -> v_pk_max_f32 / v_pk_fma_f32
__device__ inline f32x2 vmax2(f32x2 a, f32x2 b) { return __builtin_elementwise_max(a, b); }
__device__ inline f32x2 vfma2(f32x2 a, f32x2 b, f32x2 c) { return __builtin_elementwise_fma(a, b, c); }

// 16-lane (DPP row) rotate-reduce (r7): row_ror 8/4/2/1 within 16-lane rows.
template<int C> __device__ inline float rsum(float x) {
    int v = __builtin_amdgcn_update_dpp(0, __builtin_bit_cast(int, x), C, 0xf, 0xf, true);
    return x + __builtin_bit_cast(float, v);
}
template<int C> __device__ inline float rmax(float x) {
    int v = __builtin_amdgcn_update_dpp(0, __builtin_bit_cast(int, x), C, 0xf, 0xf, true);
    return fmaxf(x, __builtin_bit_cast(float, v));
}
__device__ inline float red16_sum(float x) {
    x = rsum<0x128>(x); x = rsum<0x124>(x); x = rsum<0x122>(x); x = rsum<0x121>(x);
    return x;
}
__device__ inline float red16_max(float x) {
    x = rmax<0x128>(x); x = rmax<0x124>(x); x = rmax<0x122>(x); x = rmax<0x121>(x);
    return x;
}

// ---------------------------------------------------------------------------
// convert: x fp32 -> bf16; w_qkv [512][1536] -> wqkvt [1536][512] bf16 (T);
//          w_out [512][512] -> woutt [512][512] bf16 (T)
// ---------------------------------------------------------------------------
__global__ __launch_bounds__(256) void convert_all(const float* __restrict__ x,
                                                   const float* __restrict__ wqkv,
                                                   const float* __restrict__ wout,
                                                   short* __restrict__ xb,
                                                   short* __restrict__ wqkvt,
                                                   short* __restrict__ woutt) {
    __shared__ float tl[32][33];
    const int bid = blockIdx.x;
    const int t = threadIdx.x;
    if (bid < 1024) {
        int base = bid * 2048 + t * 8;
        f32x4 v0 = *(const f32x4*)(x + base);
        f32x4 v1 = *(const f32x4*)(x + base + 4);
        u32x4 o = {packbf2(v0[0], v0[1]), packbf2(v0[2], v0[3]),
                   packbf2(v1[0], v1[1]), packbf2(v1[2], v1[3])};
        *(u32x4*)(xb + base) = o;
        return;
    }
    const float* src; short* dst; int NC, tn, tk;
    if (bid < 1024 + 768) {
        int idx = bid - 1024; tn = idx % 48; tk = idx / 48; src = wqkv; dst = wqkvt; NC = 1536;
    } else {
        int idx = bid - 1792; tn = idx % 16; tk = idx / 16; src = wout; dst = woutt; NC = 512;
    }
    const int row = t >> 3, c4 = (t & 7) * 4;
    f32x4 v = *(const f32x4*)(src + (size_t)(tk * 32 + row) * NC + tn * 32 + c4);
    tl[row][c4 + 0] = v[0]; tl[row][c4 + 1] = v[1];
    tl[row][c4 + 2] = v[2]; tl[row][c4 + 3] = v[3];
    __syncthreads();
    float a = tl[c4 + 0][row], b = tl[c4 + 1][row];
    float c = tl[c4 + 2][row], d = tl[c4 + 3][row];
    u32x2 o = {packbf2(a, b), packbf2(c, d)};
    *(u32x2*)(dst + (size_t)(tn * 32 + row) * 512 + tk * 32 + c4) = o;
}

// ---------------------------------------------------------------------------
// bf16 MFMA GEMM: BMm x BNn tile, 256 thr (4 waves, 2x2), BK=32, 2-phase dbuf.
// MODE 0 (BN=128): bn<4 -> qb (q*1/16); bn 4..7 -> kh; bn>=8 -> vt3.
// MODE 1: fp32 [M][512].
// ---------------------------------------------------------------------------
template<int NB, int MODE, int BM, int BN>
__global__ __launch_bounds__(256) void gemm_bf16(const short* __restrict__ A,
                                                 const short* __restrict__ Bt,
                                                 void* __restrict__ outp,
                                                 short* __restrict__ vt3,
                                                 short* __restrict__ kh) {
    constexpr int MFR = BM / 32;            // m-fragments per wave
    constexpr int NFR = BN / 32;            // n-fragments per wave
    constexpr int AI = BM / 64;             // gl_lds16 calls for A per step
    constexpr int BI = BN / 64;
    __shared__ __align__(16) short As[2][BM * 32];
    __shared__ __align__(16) short Bs[2][BN * 32];
    const int t = threadIdx.x;
    const int lane = t & 63;
    const int wv = t >> 6;
    const int quad = lane >> 4;
    const int l16 = lane & 15;
    const int bm = blockIdx.x / NB;
    const int bn = blockIdx.x % NB;
    const int wm = (wv & 1) * (BM / 2), wn = (wv >> 1) * (BN / 2);

    f32x4 acc[MFR][NFR];
    #pragma unroll
    for (int i = 0; i < MFR; i++)
        #pragma unroll
        for (int j = 0; j < NFR; j++) acc[i][j] = (f32x4){0.f, 0.f, 0.f, 0.f};

    const int sr = t >> 2, sc = (t & 3) * 8;
    const short* Abase = A + (size_t)(bm * BM + sr) * 512 + sc;
    const short* Bbase = Bt + (size_t)(bn * BN + sr) * 512 + sc;

    // prologue: stage kt=0 into buf 0
    #pragma unroll
    for (int i = 0; i < AI; i++)
        gl_lds16(Abase + (size_t)(64 * i) * 512, &As[0][64 * i * 32 + t * 8]);
    #pragma unroll
    for (int i = 0; i < BI; i++)
        gl_lds16(Bbase + (size_t)(64 * i) * 512, &Bs[0][64 * i * 32 + t * 8]);
    __syncthreads();

    for (int kt = 0; kt < 16; kt++) {
        const int cur = kt & 1;
        if (kt < 15) {                       // issue next-tile stage FIRST
            #pragma unroll
            for (int i = 0; i < AI; i++)
                gl_lds16(Abase + (size_t)(64 * i) * 512 + (kt + 1) * 32,
                         &As[cur ^ 1][64 * i * 32 + t * 8]);
            #pragma unroll
            for (int i = 0; i < BI; i++)
                gl_lds16(Bbase + (size_t)(64 * i) * 512 + (kt + 1) * 32,
                         &Bs[cur ^ 1][64 * i * 32 + t * 8]);
        }
        bf16x8 af[MFR], bfr[NFR];
        #pragma unroll
        for (int mi = 0; mi < MFR; mi++)
            af[mi] = *(const bf16x8*)(&As[cur][(wm + mi * 16 + l16) * 32 + quad * 8]);
        #pragma unroll
        for (int ni = 0; ni < NFR; ni++)
            bfr[ni] = *(const bf16x8*)(&Bs[cur][(wn + ni * 16 + l16) * 32 + quad * 8]);
        #pragma unroll
        for (int mi = 0; mi < MFR; mi++)
            #pragma unroll
            for (int ni = 0; ni < NFR; ni++)
                acc[mi][ni] = __builtin_amdgcn_mfma_f32_16x16x32_bf16(af[mi], bfr[ni], acc[mi][ni], 0, 0, 0);
        __syncthreads();                     // drains stage(kt+1) + guards LDS reuse
    }

    if (MODE == 0) {
        if (bn < 4) {
            // Q -> qb [4096][512], scaled 1/16
            short* ob = (short*)outp;
            #pragma unroll
            for (int mi = 0; mi < MFR; mi++)
                #pragma unroll
                for (int ni = 0; ni < NFR; ni++)
                    #pragma unroll
                    for (int rg = 0; rg < 4; rg++)
                        ob[(size_t)(bm * BM + wm + mi * 16 + quad * 4 + rg) * 512
                           + bn * BN + wn + ni * 16 + l16] = (short)f2bf(acc[mi][ni][rg] * 0.0625f);
        } else if (bn < 8) {
            // K -> kh frag layout: head (bb,hh): [j>>4][dh>>3][j&15][dh&7]
            #pragma unroll
            for (int mi = 0; mi < MFR; mi++) {
                int rowb = bm * BM + wm + mi * 16 + quad * 4;
                int bbb = rowb >> 10, jj0 = rowb & 1023;
                #pragma unroll
                for (int ni = 0; ni < NFR; ni++) {
                    int c = bn * BN + wn + ni * 16 + l16 - 512;  // 0..511
                    int hh = c >> 6, dh = c & 63;
                    short* base = kh + (size_t)(bbb * 8 + hh) * 65536
                                  + (size_t)(jj0 >> 4) * 1024 + (dh >> 3) * 128 + (dh & 7);
                    #pragma unroll
                    for (int rg = 0; rg < 4; rg++)
                        base[((jj0 & 15) + rg) * 8] = (short)f2bf(acc[mi][ni][rg]);
                }
            }
        } else {
            // V -> vt3 frag layout: head: [j>>3][d][j&7]
            #pragma unroll
            for (int mi = 0; mi < MFR; mi++) {
                int rowb = bm * BM + wm + mi * 16 + quad * 4;
                int bbb = rowb >> 10, j = rowb & 1023;
                #pragma unroll
                for (int ni = 0; ni < NFR; ni++) {
                    int vcol = bn * BN + wn + ni * 16 + l16 - 1024;  // 0..511
                    int hh = vcol >> 6, dd = vcol & 63;
                    u32x2 pk = {packbf2(acc[mi][ni][0], acc[mi][ni][1]),
                                packbf2(acc[mi][ni][2], acc[mi][ni][3])};
                    *(u32x2*)(vt3 + (size_t)(bbb * 8 + hh) * 65536
                              + (size_t)(j >> 3) * 512 + dd * 8 + (j & 7)) = pk;
                }
            }
        }
    } else {
        float* of = (float*)outp;
        #pragma unroll
        for (int mi = 0; mi < MFR; mi++)
            #pragma unroll
            for (int ni = 0; ni < NFR; ni++)
                #pragma unroll
                for (int rg = 0; rg < 4; rg++)
                    of[(size_t)(bm * BM + wm + mi * 16 + quad * 4 + rg) * 512
                       + bn * BN + wn + ni * 16 + l16] = acc[mi][ni][rg];
    }
}

// ---------------------------------------------------------------------------
// Fused entmax-1.5 attention: 16 query rows/block, 256 thr. (r13 structure)
// K/V register prefetch across the serial chain; Newton 5 iters; DPP reduce;
// setprio-wrapped pure-MFMA PV bursts; dbuf tbuf; fragment-native K/V loads.
// ---------------------------------------------------------------------------
__global__ __launch_bounds__(256, 4) void attn_entmax(const short* __restrict__ qb,
                                                      const short* __restrict__ kh,
                                                      const short* __restrict__ vt3,
                                                      short* __restrict__ oheads) {
    __shared__ __align__(16) unsigned char smem[34304];
    short* P_lds = (short*)smem;            // [16][1024] bf16, XOR-swizzled 8-blocks (32768 B)
    float* tbuf = (float*)smem;             // [2][16][268] fp32 transpose buf (34304 B)
    float* osum = (float*)smem;             // [16][68] fp32 (4352 B)
    const int TB = 16 * 268;                // floats per tbuf chunk

    const int t = threadIdx.x;
    const int lane = t & 63;
    const int wv = t >> 6;
    const int quad = lane >> 4;
    const int l16 = lane & 15;

    const int xcd = blockIdx.x & 7;
    const int g = blockIdx.x >> 3;
    const int hb = xcd * 4 + (g >> 6);      // 0..31
    const int rt = g & 63;
    const int bb = hb >> 3, hh = hb & 7;
    const int r0 = rt * 16;

    // Q A-frags from qb [4096][512]; q pre-scaled by 1/16 so z = sim/2
    bf16x8 a0, a1;
    {
        const short* qp = qb + (size_t)(bb * 1024 + r0 + l16) * 512 + hh * 64 + quad * 8;
        a0 = *(const bf16x8*)qp;
        a1 = *(const bf16x8*)(qp + 32);
    }

    const short* khh = kh + (size_t)(bb * 8 + hh) * 65536;
    const short* vb0 = vt3 + (size_t)(bb * 8 + hh) * 65536;

    // ---- scores in 4 column-chunks of 256, transposed to row-owner layout ----
    // zT2[ci*8 + i*2 + (c>>1)][c&1] = z[row quad*4+wv][col ci*256 + i*64 + l16*4 + c]
    f32x2 zT2[32];
    const int rown = quad * 4 + wv;         // owned row

    bf16x8 kc0[4], kc1[4], kn0[4], kn1[4];
    #pragma unroll
    for (int f = 0; f < 4; f++) {           // preload chunk 0 K-frags
        int supl = f >> 1, jj = f & 1;
        int jtile = supl * 8 + (wv + 4 * jj);
        const short* kp = khh + (size_t)jtile * 1024 + l16 * 8;
        kc0[f] = *(const bf16x8*)(kp + quad * 128);
        kc1[f] = *(const bf16x8*)(kp + (4 + quad) * 128);
    }

    #pragma unroll
    for (int ci = 0; ci < 4; ci++) {
        const int cb = (ci & 1) * TB;
        if (ci < 3) {                       // issue next chunk's K loads FIRST
            #pragma unroll
            for (int f = 0; f < 4; f++) {
                int supl = f >> 1, jj = f & 1;
                int jtile = ((ci + 1) * 2 + supl) * 8 + (wv + 4 * jj);
                const short* kp = khh + (size_t)jtile * 1024 + l16 * 8;
                kn0[f] = *(const bf16x8*)(kp + quad * 128);
                kn1[f] = *(const bf16x8*)(kp + (4 + quad) * 128);
            }
        }
        #pragma unroll
        for (int f = 0; f < 4; f++) {
            int supl = f >> 1, jj = f & 1;
            f32x4 acc = {0.f, 0.f, 0.f, 0.f};
            acc = __builtin_amdgcn_mfma_f32_16x16x32_bf16(a0, kc0[f], acc, 0, 0, 0);
            acc = __builtin_amdgcn_mfma_f32_16x16x32_bf16(a1, kc1[f], acc, 0, 0, 0);
            int colc = supl * 128 + (wv + 4 * jj) * 16 + l16;
            #pragma unroll
            for (int rg = 0; rg < 4; rg++)
                tbuf[cb + (quad * 4 + rg) * 268 + colc] = acc[rg];
        }
        __syncthreads();                    // tbuf[cb] complete (also orders reuse)
        #pragma unroll
        for (int i = 0; i < 4; i++) {
            f32x4 v = *(const f32x4*)(tbuf + cb + rown * 268 + i * 64 + l16 * 4);
            zT2[ci * 8 + i * 2 + 0] = (f32x2){v[0], v[1]};
            zT2[ci * 8 + i * 2 + 1] = (f32x2){v[2], v[3]};
        }
        #pragma unroll
        for (int f = 0; f < 4; f++) { kc0[f] = kn0[f]; kc1[f] = kn1[f]; }
    }
    __syncthreads();                        // last readback done; smem reusable

    // ---- init: mx + full-support closed-form tau, clamped to bracket ----
    float tau;
    {
        f32x2 m2 = zT2[0], p2 = zT2[0];
        f32x2 q2 = zT2[0] * zT2[0];
        #pragma unroll
        for (int i = 1; i < 32; i++) {
            f32x2 v = zT2[i];
            m2 = vmax2(m2, v);
            p2 = p2 + v;
            q2 = vfma2(v, v, q2);
        }
        float mx = red16_max(fmaxf(m2[0], m2[1]));
        float s1 = red16_sum(p2[0] + p2[1]);
        float s2 = red16_sum(q2[0] + q2[1]);
        float mean = s1 * (1.0f / 1024.0f);
        float disc = fmaxf(mean * mean - (s2 - 1.0f) * (1.0f / 1024.0f), 0.0f);
        tau = mean - __builtin_sqrtf(disc);
        tau = fminf(tau, mx - 0.03125f);    // tau* <= mx - 1/sqrt(n)
        tau = fmaxf(tau, mx - 1.0f);        // tau* >= mx - 1
    }

    // ---- Newton (barrier-free, packed fp32): f(tau)=sum relu(z-tau)^2 - 1 ----
    const f32x2 zero2 = {0.f, 0.f};
    #pragma unroll 1
    for (int it = 0; it < 5; it++) {
        f32x2 tau2 = {tau, tau};
        f32x2 s1a = zero2, s1b = zero2, s2a = zero2, s2b = zero2;
        #pragma unroll
        for (int i = 0; i < 16; i++) {
            f32x2 ra = vmax2(zT2[i * 2] - tau2, zero2);
            f32x2 rb = vmax2(zT2[i * 2 + 1] - tau2, zero2);
            s1a = s1a + ra; s1b = s1b + rb;
            s2a = vfma2(ra, ra, s2a); s2b = vfma2(rb, rb, s2b);
        }
        float s1 = red16_sum((s1a[0] + s1a[1]) + (s1b[0] + s1b[1]));
        float s2 = red16_sum((s2a[0] + s2a[1]) + (s2b[0] + s2b[1]));
        tau += (s2 - 1.0f) * 0.5f * __builtin_amdgcn_rcpf(s1);
    }

    // ---- P = relu(z-tau)^2 -> swizzled P_lds (bf16, A-operand layout) ----
    // off(row, j) = row*1024 + ((jb ^ (row&7))<<3) + (j&7), jb = j>>3
    {
        const f32x2 tau2 = {tau, tau};
        const int dg = l16;
        const int ra = rown & 7;
        #pragma unroll
        for (int ci = 0; ci < 4; ci++)
            #pragma unroll
            for (int i = 0; i < 4; i++) {
                f32x2 r01 = vmax2(zT2[ci * 8 + i * 2] - tau2, zero2);
                f32x2 r23 = vmax2(zT2[ci * 8 + i * 2 + 1] - tau2, zero2);
                f32x2 p01 = r01 * r01, p23 = r23 * r23;
                u32x2 pk = {packbf2(p01[0], p01[1]), packbf2(p23[0], p23[1])};
                int jb = ci * 32 + i * 8 + (dg >> 1);
                *(u32x2*)(P_lds + rown * 1024 + ((jb ^ ra) << 3) + (dg & 1) * 4) = pk;
            }
    }
    __syncthreads();

    // ---- PV from vt3 frag layout: O[r][d] += P[r][j] V[j][d] ----
    f32x4 oacc[4];
    #pragma unroll
    for (int nt = 0; nt < 4; nt++) oacc[nt] = (f32x4){0.f, 0.f, 0.f, 0.f};
    const int lra = l16 & 7;
    bf16x8 bv[4], bvn[4];
    {
        int jb0 = wv * 4 + quad;            // sup = 0
        const short* vs = vb0 + (size_t)jb0 * 512;
        #pragma unroll
        for (int nt = 0; nt < 4; nt++)
            bv[nt] = *(const bf16x8*)(vs + (nt * 16 + l16) * 8);
    }
    #pragma unroll
    for (int sup = 0; sup < 8; sup++) {
        int jb = sup * 16 + wv * 4 + quad;
        bf16x8 pf = *(const bf16x8*)(P_lds + l16 * 1024 + ((jb ^ lra) << 3));
        if (sup < 7) {                      // prefetch next sup's V-frags
            const short* vs = vb0 + (size_t)(jb + 16) * 512;
            #pragma unroll
            for (int nt = 0; nt < 4; nt++)
                bvn[nt] = *(const bf16x8*)(vs + (nt * 16 + l16) * 8);
        }
        __builtin_amdgcn_s_setprio(1);
        #pragma unroll
        for (int nt = 0; nt < 4; nt++)
            oacc[nt] = __builtin_amdgcn_mfma_f32_16x16x32_bf16(pf, bv[nt], oacc[nt], 0, 0, 0);
        __builtin_amdgcn_s_setprio(0);
        #pragma unroll
        for (int nt = 0; nt < 4; nt++) bv[nt] = bvn[nt];
    }
    __syncthreads();                        // all P reads done; overlay osum

    #pragma unroll
    for (int nt = 0; nt < 4; nt++)
        #pragma unroll
        for (int rg = 0; rg < 4; rg++)
            osum[(wv * 16 + quad * 4 + rg) * 68 + nt * 16 + l16] = oacc[nt][rg];
    __syncthreads();
    #pragma unroll
    for (int i = 0; i < 2; i++) {
        int idx = t + 256 * i;
        int r = idx >> 5, dp = idx & 31;
        float e0 = 0.f, e1 = 0.f;
        #pragma unroll
        for (int w = 0; w < 4; w++) {
            e0 += osum[(w * 16 + r) * 68 + dp * 2];
            e1 += osum[(w * 16 + r) * 68 + dp * 2 + 1];
        }
        *(uint32_t*)(oheads + (size_t)(bb * 1024 + r0 + r) * 512 + hh * 64 + dp * 2) = packbf2(e0, e1);
    }
}

// ---------------------------------------------------------------------------
extern "C" void kernel_launch(void* const* d_in, const int* in_sizes, int n_in,
                              void* d_out, int out_size, void* d_ws, size_t ws_size,
                              hipStream_t stream) {
    (void)in_sizes; (void)n_in; (void)out_size; (void)ws_size;
    const float* x     = (const float*)d_in[0];
    const float* w_qkv = (const float*)d_in[1];
    const float* w_out = (const float*)d_in[2];
    float* out = (float*)d_out;

    char* ws = (char*)d_ws;
    short* qb    = (short*)(ws);                        // 4,194,304 B  Q [4096][512]
    short* kh    = (short*)(ws + 4194304);              // 4,194,304 B  K frag-layout
    short* vt3   = (short*)(ws + 8388608);              // 4,194,304 B  V frag-layout
    short* ohead = (short*)(ws + 12582912);             // 4,194,304 B
    short* xb    = (short*)(ws + 16777216);             // 4,194,304 B
    short* wqkvt = (short*)(ws + 20971520);             // 1,572,864 B
    short* woutt = (short*)(ws + 22544384);             //   524,288 B

    convert_all<<<dim3(2048), dim3(256), 0, stream>>>(x, w_qkv, w_out, xb, wqkvt, woutt);
    gemm_bf16<12, 0, 128, 128><<<dim3(32 * 12), dim3(256), 0, stream>>>(xb, wqkvt, (void*)qb, vt3, kh);
    attn_entmax<<<dim3(2048), dim3(256), 0, stream>>>(qb, kh, vt3, ohead);
    gemm_bf16<8, 1, 64, 64><<<dim3(64 * 8), dim3(256), 0, stream>>>(ohead, woutt, (void*)out, nullptr, nullptr);
}